// Round 10
// baseline (317.060 us; speedup 1.0000x reference)
//
#include <hip/hip_runtime.h>

// VQ nearest-codebook: MFMA bf16 hi/lo filter + exact fp32-emulated rescore.
// R9:  block-shared B-frags, dbuf LDS + global_load_lds(16B); packed top-2.
// R10: v_med3_u32 2nd-best; v_cvt_pk_bf16_f32 A-prep.
// R11: FAILED split-K (spill). R12: 32 waves/CU neutral. R13: deferred
//      epilogue -12%. R14/R15: barrier restructures ~neutral. R15-probe:
//      NOSTAGE 52us = MFMA 25 + epilogue-VALU 26 + A-prep 4 (SERIAL);
//      memory path only ~12us. R16: group-8 rotation FAILED (2 blk/CU).
// R17 (this round): shrink the VALU term exactly:
//      (a) filter ranks by (1.75 - dot): se (<= 64/1024^2 = 6.1e-5, tiny by
//          codebook construction) moved INTO the rescore margin -> no per-
//          chunk acc-init movs (all chains start from one immutable cinit
//          quad via MFMA C operand), no se2 LDS/staging;
//      (b) d in [1.56,1.94] subset [1.5,2) (|dot| <= 2||x||||e|| <= 0.19)
//          -> sign/exp/mantissa-MSB constant -> 1-op pack p=(u<<10)|code.
//      Epilogue+init 80 -> 48 VALU/chunk. Margin 1e-4 value (ref rounding
//      1.5e-5 + bf16 3-term 1.1e-5 + se spread 6.2e-5 + slack) = 900000
//      packed (Dp = Dd*2^33). Rescore set ~3x -> grid 2048.
//
// ref semantics (verified R2/R3/R6/R8): d[n,k] = fl(fl(sx+se) - chain),
// sx/se = numpy pairwise-8 tree of squares, chain = sequential FMA over d of
// (2x)*e, argmin first-index tie-break. Rows whose filter gap <= margin get
// the exact fp32-emulated rescore (covers se reordering + all approx error).

#define D 64
#define K 1024
#define HW 4096
#define NTOTAL 131072

// workspace layout (bytes)
#define BF_OFF   0          // B-frags: 32 chunks * 8 frags * 64 lanes * 16B = 256 KB
#define SE_OFF   262144     // 4 KB raw se (rescore)
#define CNT_OFF  270336
#define LIST_OFF 270340
#define LIST_CAP 65536
#define WS_NEED  (270340 + LIST_CAP * 4)

// packed-gap margin: 1e-4 value gap * 2^33 packed/value ~= 859k -> 900000.
#define MARGIN_P 900000u

typedef __attribute__((ext_vector_type(8))) short bf16x8;   // 8 bf16 = 4 VGPR
typedef __attribute__((ext_vector_type(4))) float f32x4;
typedef __attribute__((ext_vector_type(4))) unsigned int u32x4;

__device__ __forceinline__ unsigned short bf16_rne(float f) {
    unsigned u = __float_as_uint(f);
    u += 0x7fffu + ((u >> 16) & 1u);
    return (unsigned short)(u >> 16);
}
__device__ __forceinline__ float bf16_to_f(unsigned short h) {
    return __uint_as_float(((unsigned)h) << 16);
}

// HW packed f32->bf16 RNE convert: low16 = bf16(a), high16 = bf16(b).
__device__ __forceinline__ unsigned cvt_pk_bf16(float a, float b) {
    unsigned r;
    asm("v_cvt_pk_bf16_f32 %0, %1, %2" : "=v"(r) : "v"(a), "v"(b));
    return r;
}

// numpy pairwise sum, n=64
__device__ __forceinline__ float np_sumsq64(const float* v) {
    float r[8];
#pragma unroll
    for (int j = 0; j < 8; ++j) r[j] = __fmul_rn(v[j], v[j]);
#pragma unroll
    for (int i = 8; i < 64; i += 8)
#pragma unroll
        for (int j = 0; j < 8; ++j)
            r[j] = __fadd_rn(r[j], __fmul_rn(v[i + j], v[i + j]));
    float s01 = __fadd_rn(r[0], r[1]), s23 = __fadd_rn(r[2], r[3]);
    float s45 = __fadd_rn(r[4], r[5]), s67 = __fadd_rn(r[6], r[7]);
    return __fadd_rn(__fadd_rn(s01, s23), __fadd_rn(s45, s67));
}

// --- prep: codebook -> se + B-frags in lane order; zeroes CNT ---
__global__ __launch_bounds__(256) void prep_cb(const float* __restrict__ cb,
                                               char* __restrict__ ws) {
    if (blockIdx.x == 0 && threadIdx.x == 0) *(int*)(ws + CNT_OFF) = 0;
    int k = blockIdx.x * 256 + threadIdx.x;          // grid 4*256 = 1024
    const float* e = cb + k * D;
    float v[D];
#pragma unroll
    for (int d = 0; d < D; ++d) v[d] = e[d];
    ((float*)(ws + SE_OFF))[k] = np_sumsq64(v);
    unsigned short hh[D], ll[D];
#pragma unroll
    for (int d = 0; d < D; ++d) {
        hh[d] = bf16_rne(v[d]);
        ll[d] = bf16_rne(v[d] - bf16_to_f(hh[d]));
    }
    const int c = k >> 5, tc = (k >> 4) & 1, c16 = k & 15;
    uint4* bf = (uint4*)(ws + BF_OFF);
#pragma unroll
    for (int qd = 0; qd < 8; ++qd) {                 // d0 = qd*8
        int q = qd & 3, jh = qd >> 2;                // d0 = q*8 + 32*jh
        int l = q * 16 + c16;
        uint4 a, b;
        const unsigned short* h = hh + qd * 8;
        const unsigned short* lo = ll + qd * 8;
        a.x = h[0] | (h[1] << 16);  a.y = h[2] | (h[3] << 16);
        a.z = h[4] | (h[5] << 16);  a.w = h[6] | (h[7] << 16);
        b.x = lo[0] | (lo[1] << 16); b.y = lo[2] | (lo[3] << 16);
        b.z = lo[4] | (lo[5] << 16); b.w = lo[6] | (lo[7] << 16);
        bf[(c * 8 + tc * 4 + jh) * 64 + l]       = a;   // hi -> j=jh
        bf[(c * 8 + tc * 4 + 2 + jh) * 64 + l]   = b;   // lo -> j=2+jh
    }
}

// --- main: 256 threads = 4 waves, 128 rows/block, grid 1024.
//     Pair-barrier dbuf (R15 structure) + constant-C MFMA + 1-op pack. ---
__global__ __launch_bounds__(256, 4) void vq_main(const float* __restrict__ in,
                                                  const float* __restrict__ cb,
                                                  float* __restrict__ out,
                                                  char* __restrict__ ws) {
    __shared__ uint4 s_bf[2][2][8][64];   // [set][chunk-in-pair][frag][lane] = 32 KB
    __shared__ int s_widx[128];

    const int t = threadIdx.x;
    const int nb = blockIdx.x * 128;          // grid 1024
    const int b = nb >> 12, hw0 = nb & (HW - 1);
    const int lane = t & 63, q = lane >> 4, c16 = lane & 15, w = t >> 6;

    // ---- A-frags direct from global. A = -(2x), hi/lo split via HW cvt_pk.
    bf16x8 af[2][4];
#pragma unroll
    for (int tv = 0; tv < 2; ++tv) {
        const float* xp = in + (size_t)b * (D * HW) + hw0 + w * 32 + tv * 16 + c16;
#pragma unroll
        for (int jh = 0; jh < 2; ++jh) {
            float ny[8];
#pragma unroll
            for (int i = 0; i < 8; ++i)
                ny[i] = __fmul_rn(xp[(size_t)(jh * 32 + q * 8 + i) * HW], -2.0f);
            u32x4 hv, lv;
#pragma unroll
            for (int p = 0; p < 4; ++p) {
                unsigned hp = cvt_pk_bf16(ny[2 * p], ny[2 * p + 1]);
                float h0 = __uint_as_float(hp << 16);
                float h1 = __uint_as_float(hp & 0xFFFF0000u);
                unsigned lp = cvt_pk_bf16(__fsub_rn(ny[2 * p], h0),
                                          __fsub_rn(ny[2 * p + 1], h1));
                hv[p] = hp; lv[p] = lp;
            }
            af[tv][jh]     = __builtin_bit_cast(bf16x8, hv);   // j=0,1: hi
            af[tv][2 + jh] = __builtin_bit_cast(bf16x8, lv);   // j=2,3: lo
        }
    }

    const char* bfbase = ws + BF_OFF;

    // immutable C-init quad: d = 1.75 - dot  in [1.56, 1.94] (|dot|<=0.19)
    const f32x4 cinit = {1.75f, 1.75f, 1.75f, 1.75f};

    auto stage_chunk = [&](int c, int set, int u) {
        const char* g = bfbase + ((size_t)(c * 8 + 2 * w) * 64 + lane) * 16;
        __builtin_amdgcn_global_load_lds((const __attribute__((address_space(1))) void*)g,
            (__attribute__((address_space(3))) void*)&s_bf[set][u][2 * w][0], 16, 0, 0);
        __builtin_amdgcn_global_load_lds((const __attribute__((address_space(1))) void*)(g + 1024),
            (__attribute__((address_space(3))) void*)&s_bf[set][u][2 * w + 1][0], 16, 0, 0);
    };

    unsigned p1[8], p2[8];
#pragma unroll
    for (int s = 0; s < 8; ++s) { p1[s] = 0xFFFFFFFFu; p2[s] = 0xFFFFFFFFu; }

    // epilogue: d in [1.5,2) -> sign/exp/mantissa-MSB constant -> p=(u<<10)|code
    // is value-monotone with numpy tie-break. 3 VALU/candidate.
    auto epilogue = [&](int c, const f32x4 (&acc)[2][2]) {
#pragma unroll
        for (int tv = 0; tv < 2; ++tv)
#pragma unroll
            for (int tc = 0; tc < 2; ++tc) {
                unsigned code = (unsigned)(c * 32 + tc * 16 + c16);
#pragma unroll
                for (int r = 0; r < 4; ++r) {
                    unsigned u = __float_as_uint(acc[tv][tc][r]);
                    unsigned p = (u << 10) | code;
                    int s = tv * 4 + r;
                    unsigned m;
                    asm("v_med3_u32 %0, %1, %2, %3"
                        : "=v"(m) : "v"(p), "v"(p1[s]), "v"(p2[s]));
                    p2[s] = m;
                    p1[s] = p < p1[s] ? p : p1[s];
                }
            }
    };
    const int sa[6] = {0, 1, 2, 3, 0, 1};
    const int sb[6] = {0, 1, 0, 1, 2, 3};

    f32x4 accE[2][2], accO[2][2];
    bf16x8 bfr[2][4];

    // prologue: stage pair 0 into set 0
    stage_chunk(0, 0, 0);
    stage_chunk(1, 0, 1);

    int set = 0;
    for (int p = 0; p < 16; ++p) {
        const int ce = 2 * p, co = 2 * p + 1;

        asm volatile("s_waitcnt vmcnt(0)" ::: "memory");
        __builtin_amdgcn_s_barrier();
        __builtin_amdgcn_sched_barrier(0);
        if (p < 15) {
            stage_chunk(ce + 2, set ^ 1, 0);
            stage_chunk(co + 2, set ^ 1, 1);
        }

        // ---- even chunk: bfr reads, deferred epi(prev), MFMAs from cinit
        {
#pragma unroll
            for (int tc = 0; tc < 2; ++tc)
#pragma unroll
                for (int j = 0; j < 4; ++j)
                    bfr[tc][j] = *(const bf16x8*)&s_bf[set][0][tc * 4 + j][lane];
            if (p != 0) epilogue(ce - 1, accO);
            __builtin_amdgcn_s_setprio(1);
#pragma unroll
            for (int tv = 0; tv < 2; ++tv)
#pragma unroll
                for (int tc = 0; tc < 2; ++tc)
                    accE[tv][tc] = __builtin_amdgcn_mfma_f32_16x16x32_bf16(
                        af[tv][0], bfr[tc][0], cinit, 0, 0, 0);
#pragma unroll
            for (int s = 1; s < 6; ++s)
#pragma unroll
                for (int tv = 0; tv < 2; ++tv)
#pragma unroll
                    for (int tc = 0; tc < 2; ++tc)
                        accE[tv][tc] = __builtin_amdgcn_mfma_f32_16x16x32_bf16(
                            af[tv][sa[s]], bfr[tc][sb[s]], accE[tv][tc], 0, 0, 0);
            __builtin_amdgcn_s_setprio(0);
        }

        // ---- odd chunk (no barrier inside the pair)
        {
#pragma unroll
            for (int tc = 0; tc < 2; ++tc)
#pragma unroll
                for (int j = 0; j < 4; ++j)
                    bfr[tc][j] = *(const bf16x8*)&s_bf[set][1][tc * 4 + j][lane];
            epilogue(ce, accE);
            __builtin_amdgcn_s_setprio(1);
#pragma unroll
            for (int tv = 0; tv < 2; ++tv)
#pragma unroll
                for (int tc = 0; tc < 2; ++tc)
                    accO[tv][tc] = __builtin_amdgcn_mfma_f32_16x16x32_bf16(
                        af[tv][0], bfr[tc][0], cinit, 0, 0, 0);
#pragma unroll
            for (int s = 1; s < 6; ++s)
#pragma unroll
                for (int tv = 0; tv < 2; ++tv)
#pragma unroll
                    for (int tc = 0; tc < 2; ++tc)
                        accO[tv][tc] = __builtin_amdgcn_mfma_f32_16x16x32_bf16(
                            af[tv][sa[s]], bfr[tc][sb[s]], accO[tv][tc], 0, 0, 0);
            __builtin_amdgcn_s_setprio(0);
        }
        set ^= 1;
    }
    epilogue(31, accO);

    // ---- cross-lane top-2 merge over the 16 col-lanes (bits 0-3 of lane)
#pragma unroll
    for (int m = 1; m < 16; m <<= 1)
#pragma unroll
        for (int s = 0; s < 8; ++s) {
            unsigned o1 = (unsigned)__shfl_xor((int)p1[s], m, 64);
            unsigned o2 = (unsigned)__shfl_xor((int)p2[s], m, 64);
            unsigned lo = p1[s] < o1 ? p1[s] : o1;
            unsigned hi = p1[s] < o1 ? o1 : p1[s];
            unsigned n2 = p2[s] < o2 ? p2[s] : o2;
            p2[s] = hi < n2 ? hi : n2;
            p1[s] = lo;
        }

    if (c16 == 0) {
#pragma unroll
        for (int s = 0; s < 8; ++s) {
            int tv = s >> 2, r = s & 3;
            int row = w * 32 + tv * 16 + q * 4 + r;    // block-local
            s_widx[row] = (int)(p1[s] & 1023u);
            if (p2[s] - p1[s] <= MARGIN_P) {
                int pos = atomicAdd((int*)(ws + CNT_OFF), 1);
                if (pos < LIST_CAP) ((int*)(ws + LIST_OFF))[pos] = nb + row;
            }
        }
    }
    __syncthreads();

    // ---- gather-write (stores coalesced across rows)
    {
        int r = t & 127, half = t >> 7;
        int widx = s_widx[r];
        const float4* er = (const float4*)(cb + (size_t)widx * D + half * 32);
        float* op = out + (size_t)b * (D * HW) + hw0 + r + (size_t)(half * 32) * HW;
#pragma unroll
        for (int i = 0; i < 8; ++i) {
            float4 v = er[i];
            op[(size_t)(i * 4 + 0) * HW] = v.x;
            op[(size_t)(i * 4 + 1) * HW] = v.y;
            op[(size_t)(i * 4 + 2) * HW] = v.z;
            op[(size_t)(i * 4 + 3) * HW] = v.w;
        }
    }
}

// --- rescore: exact fp32-emulated chain over all codes for flagged vectors ---
__global__ __launch_bounds__(64) void vq_rescore(const float* __restrict__ in,
                                                 const float* __restrict__ cb,
                                                 float* __restrict__ out,
                                                 char* __restrict__ ws) {
    int count = *(const int*)(ws + CNT_OFF);
    if (count > LIST_CAP) count = LIST_CAP;
    const int* list = (const int*)(ws + LIST_OFF);
    const float* seg = (const float*)(ws + SE_OFF);
    int lane = threadIdx.x;
    for (int i = blockIdx.x; i < count; i += gridDim.x) {
        int n = list[i];
        int b = n >> 12, hw = n & (HW - 1);
        const float* xin = in + (size_t)b * (D * HW) + hw;
        float x[D];
#pragma unroll
        for (int d = 0; d < D; ++d) x[d] = xin[(size_t)d * HW];
        float y[D];
#pragma unroll
        for (int d = 0; d < D; ++d) y[d] = __fadd_rn(x[d], x[d]);
        float sx = np_sumsq64(x);
        float best = 3.4e38f; int bidx = 0;
        for (int c = 0; c < 16; ++c) {
            int k = c * 64 + lane;                      // ascending k per lane
            const float4* e4 = (const float4*)(cb + (size_t)k * D);
            float acc = 0.f;
#pragma unroll
            for (int p = 0; p < 16; ++p) {              // exact sequential chain
                float4 ev = e4[p];
                acc = __fmaf_rn(y[p * 4 + 0], ev.x, acc);
                acc = __fmaf_rn(y[p * 4 + 1], ev.y, acc);
                acc = __fmaf_rn(y[p * 4 + 2], ev.z, acc);
                acc = __fmaf_rn(y[p * 4 + 3], ev.w, acc);
            }
            float dist = __fsub_rn(__fadd_rn(sx, seg[k]), acc);
            if (dist < best) { best = dist; bidx = k; }
        }
#pragma unroll
        for (int m = 1; m < 64; m <<= 1) {              // (val, idx) lex-min
            float ob = __shfl_xor(best, m, 64);
            int oi = __shfl_xor(bidx, m, 64);
            if (ob < best || (ob == best && oi < bidx)) { best = ob; bidx = oi; }
        }
        out[(size_t)b * (D * HW) + (size_t)lane * HW + hw] = cb[(size_t)bidx * D + lane];
    }
}

extern "C" void kernel_launch(void* const* d_in, const int* in_sizes, int n_in,
                              void* d_out, int out_size, void* d_ws, size_t ws_size,
                              hipStream_t stream) {
    const float* in = (const float*)d_in[0];
    const float* cb = (const float*)d_in[1];
    float* out = (float*)d_out;
    char* ws = (char*)d_ws;

    if (ws_size < (size_t)WS_NEED) return;   // fail visibly, never OOB

    prep_cb<<<dim3(K / 256), dim3(256), 0, stream>>>(cb, ws);
    vq_main<<<dim3(NTOTAL / 128), dim3(256), 0, stream>>>(in, cb, out, ws);
    vq_rescore<<<dim3(2048), dim3(64), 0, stream>>>(in, cb, out, ws);
}

// Round 11
// 178.227 us; speedup vs baseline: 1.7790x; 1.7790x over previous
//
#include <hip/hip_runtime.h>

// VQ nearest-codebook: MFMA bf16 hi/lo filter + exact fp32-emulated rescore.
// R9:  block-shared B-frags, dbuf LDS + global_load_lds(16B); packed top-2.
// R10: v_med3_u32 2nd-best; v_cvt_pk_bf16_f32 A-prep.
// R11: FAILED split-K (spill). R12: 32 waves/CU neutral. R13: deferred
//      epilogue -12%. R14/R15: barrier restructures ~neutral. R15-probe:
//      NOSTAGE 52us = MFMA 25 + epi-VALU 26 + A-prep 4; memory ~12us.
// R16: group-8 rotation FAILED (2 blk/CU). R17: dot-only filter + 1-op pack:
//      vq_main 63->~48us BUT margin had to absorb worst-case se (6.1e-5) ->
//      rescore set ~20x -> rescore 161us L2-BW-bound (row x 256KB codebook).
// R18 (this round): keep R17 mechanics, restore se in the filter: C-init =
//      se+1.75 via one-time LDS copy (R15: init ~free). d stays in [1.5,2) ->
//      1-op pack still valid and now LOSSLESS -> margin back to the verified
//      3.05e-5 value = 262144 packed (256 d-ulps x 1024). Flag count ~1-2k.
//
// ref semantics (verified R2/R3/R6/R8): d[n,k] = fl(fl(sx+se) - chain),
// sx/se = numpy pairwise-8 tree of squares, chain = sequential FMA over d of
// (2x)*e, argmin first-index tie-break. Rows whose filter gap <= margin get
// the exact fp32-emulated rescore.

#define D 64
#define K 1024
#define HW 4096
#define NTOTAL 131072

// workspace layout (bytes)
#define BF_OFF   0          // B-frags: 32 chunks * 8 frags * 64 lanes * 16B = 256 KB
#define SE_OFF   262144     // 4 KB raw se (rescore)
#define SE2_OFF  266240     // 4 KB se+1.75 (main C-init)
#define CNT_OFF  270336
#define LIST_OFF 270340
#define LIST_CAP 65536
#define WS_NEED  (270340 + LIST_CAP * 4)

// packed-gap margin: 3.05e-5 value (verified budget: 2 ref fp32 roundings
// ~1.5e-5 + bf16 3-term ~1.1e-5 + slack; pack is lossless now).
// 256 d-ulps * 1024 packed/ulp = 262144.
#define MARGIN_P 262144u

typedef __attribute__((ext_vector_type(8))) short bf16x8;   // 8 bf16 = 4 VGPR
typedef __attribute__((ext_vector_type(4))) float f32x4;
typedef __attribute__((ext_vector_type(4))) unsigned int u32x4;

__device__ __forceinline__ unsigned short bf16_rne(float f) {
    unsigned u = __float_as_uint(f);
    u += 0x7fffu + ((u >> 16) & 1u);
    return (unsigned short)(u >> 16);
}
__device__ __forceinline__ float bf16_to_f(unsigned short h) {
    return __uint_as_float(((unsigned)h) << 16);
}

// HW packed f32->bf16 RNE convert: low16 = bf16(a), high16 = bf16(b).
__device__ __forceinline__ unsigned cvt_pk_bf16(float a, float b) {
    unsigned r;
    asm("v_cvt_pk_bf16_f32 %0, %1, %2" : "=v"(r) : "v"(a), "v"(b));
    return r;
}

// numpy pairwise sum, n=64
__device__ __forceinline__ float np_sumsq64(const float* v) {
    float r[8];
#pragma unroll
    for (int j = 0; j < 8; ++j) r[j] = __fmul_rn(v[j], v[j]);
#pragma unroll
    for (int i = 8; i < 64; i += 8)
#pragma unroll
        for (int j = 0; j < 8; ++j)
            r[j] = __fadd_rn(r[j], __fmul_rn(v[i + j], v[i + j]));
    float s01 = __fadd_rn(r[0], r[1]), s23 = __fadd_rn(r[2], r[3]);
    float s45 = __fadd_rn(r[4], r[5]), s67 = __fadd_rn(r[6], r[7]);
    return __fadd_rn(__fadd_rn(s01, s23), __fadd_rn(s45, s67));
}

// --- prep: codebook -> se, se+1.75, B-frags in lane order; zeroes CNT ---
__global__ __launch_bounds__(256) void prep_cb(const float* __restrict__ cb,
                                               char* __restrict__ ws) {
    if (blockIdx.x == 0 && threadIdx.x == 0) *(int*)(ws + CNT_OFF) = 0;
    int k = blockIdx.x * 256 + threadIdx.x;          // grid 4*256 = 1024
    const float* e = cb + k * D;
    float v[D];
#pragma unroll
    for (int d = 0; d < D; ++d) v[d] = e[d];
    float se = np_sumsq64(v);
    ((float*)(ws + SE_OFF))[k] = se;
    ((float*)(ws + SE2_OFF))[k] = __fadd_rn(se, 1.75f);
    unsigned short hh[D], ll[D];
#pragma unroll
    for (int d = 0; d < D; ++d) {
        hh[d] = bf16_rne(v[d]);
        ll[d] = bf16_rne(v[d] - bf16_to_f(hh[d]));
    }
    const int c = k >> 5, tc = (k >> 4) & 1, c16 = k & 15;
    uint4* bf = (uint4*)(ws + BF_OFF);
#pragma unroll
    for (int qd = 0; qd < 8; ++qd) {                 // d0 = qd*8
        int q = qd & 3, jh = qd >> 2;                // d0 = q*8 + 32*jh
        int l = q * 16 + c16;
        uint4 a, b;
        const unsigned short* h = hh + qd * 8;
        const unsigned short* lo = ll + qd * 8;
        a.x = h[0] | (h[1] << 16);  a.y = h[2] | (h[3] << 16);
        a.z = h[4] | (h[5] << 16);  a.w = h[6] | (h[7] << 16);
        b.x = lo[0] | (lo[1] << 16); b.y = lo[2] | (lo[3] << 16);
        b.z = lo[4] | (lo[5] << 16); b.w = lo[6] | (lo[7] << 16);
        bf[(c * 8 + tc * 4 + jh) * 64 + l]       = a;   // hi -> j=jh
        bf[(c * 8 + tc * 4 + 2 + jh) * 64 + l]   = b;   // lo -> j=2+jh
    }
}

// --- main: 256 threads = 4 waves, 128 rows/block, grid 1024.
//     Pair-barrier dbuf + se-in-C-init MFMA + lossless 1-op pack. ---
__global__ __launch_bounds__(256, 4) void vq_main(const float* __restrict__ in,
                                                  const float* __restrict__ cb,
                                                  float* __restrict__ out,
                                                  char* __restrict__ ws) {
    __shared__ uint4 s_bf[2][2][8][64];   // [set][chunk-in-pair][frag][lane] = 32 KB
    __shared__ float s_se2[K];            // 4 KB: se+1.75, staged once
    __shared__ int s_widx[128];

    const int t = threadIdx.x;
    const int nb = blockIdx.x * 128;          // grid 1024
    const int b = nb >> 12, hw0 = nb & (HW - 1);
    const int lane = t & 63, q = lane >> 4, c16 = lane & 15, w = t >> 6;

    // ---- A-frags direct from global. A = -(2x), hi/lo split via HW cvt_pk.
    bf16x8 af[2][4];
#pragma unroll
    for (int tv = 0; tv < 2; ++tv) {
        const float* xp = in + (size_t)b * (D * HW) + hw0 + w * 32 + tv * 16 + c16;
#pragma unroll
        for (int jh = 0; jh < 2; ++jh) {
            float ny[8];
#pragma unroll
            for (int i = 0; i < 8; ++i)
                ny[i] = __fmul_rn(xp[(size_t)(jh * 32 + q * 8 + i) * HW], -2.0f);
            u32x4 hv, lv;
#pragma unroll
            for (int p = 0; p < 4; ++p) {
                unsigned hp = cvt_pk_bf16(ny[2 * p], ny[2 * p + 1]);
                float h0 = __uint_as_float(hp << 16);
                float h1 = __uint_as_float(hp & 0xFFFF0000u);
                unsigned lp = cvt_pk_bf16(__fsub_rn(ny[2 * p], h0),
                                          __fsub_rn(ny[2 * p + 1], h1));
                hv[p] = hp; lv[p] = lp;
            }
            af[tv][jh]     = __builtin_bit_cast(bf16x8, hv);   // j=0,1: hi
            af[tv][2 + jh] = __builtin_bit_cast(bf16x8, lv);   // j=2,3: lo
        }
    }

    const char* bfbase = ws + BF_OFF;

    // one-time: se2 -> LDS (256 threads x 16B = 4 KB)
    __builtin_amdgcn_global_load_lds(
        (const __attribute__((address_space(1))) void*)(ws + SE2_OFF + (size_t)t * 16),
        (__attribute__((address_space(3))) void*)&s_se2[t * 4], 16, 0, 0);

    auto stage_chunk = [&](int c, int set, int u) {
        const char* g = bfbase + ((size_t)(c * 8 + 2 * w) * 64 + lane) * 16;
        __builtin_amdgcn_global_load_lds((const __attribute__((address_space(1))) void*)g,
            (__attribute__((address_space(3))) void*)&s_bf[set][u][2 * w][0], 16, 0, 0);
        __builtin_amdgcn_global_load_lds((const __attribute__((address_space(1))) void*)(g + 1024),
            (__attribute__((address_space(3))) void*)&s_bf[set][u][2 * w + 1][0], 16, 0, 0);
    };

    unsigned p1[8], p2[8];
#pragma unroll
    for (int s = 0; s < 8; ++s) { p1[s] = 0xFFFFFFFFu; p2[s] = 0xFFFFFFFFu; }

    // epilogue: d = se+1.75-dot in [1.58,1.92] subset [1.5,2) -> sign/exp/
    // mantissa-MSB constant -> p=(u<<10)|code value-monotone, lossless.
    auto epilogue = [&](int c, const f32x4 (&acc)[2][2]) {
#pragma unroll
        for (int tv = 0; tv < 2; ++tv)
#pragma unroll
            for (int tc = 0; tc < 2; ++tc) {
                unsigned code = (unsigned)(c * 32 + tc * 16 + c16);
#pragma unroll
                for (int r = 0; r < 4; ++r) {
                    unsigned u = __float_as_uint(acc[tv][tc][r]);
                    unsigned p = (u << 10) | code;
                    int s = tv * 4 + r;
                    unsigned m;
                    asm("v_med3_u32 %0, %1, %2, %3"
                        : "=v"(m) : "v"(p), "v"(p1[s]), "v"(p2[s]));
                    p2[s] = m;
                    p1[s] = p < p1[s] ? p : p1[s];
                }
            }
    };
    const int sa[6] = {0, 1, 2, 3, 0, 1};
    const int sb[6] = {0, 1, 0, 1, 2, 3};

    f32x4 accE[2][2], accO[2][2];
    bf16x8 bfr[2][4];

    // prologue: stage pair 0 into set 0
    stage_chunk(0, 0, 0);
    stage_chunk(1, 0, 1);

    int set = 0;
    for (int p = 0; p < 16; ++p) {
        const int ce = 2 * p, co = 2 * p + 1;

        asm volatile("s_waitcnt vmcnt(0)" ::: "memory");
        __builtin_amdgcn_s_barrier();
        __builtin_amdgcn_sched_barrier(0);
        if (p < 15) {
            stage_chunk(ce + 2, set ^ 1, 0);
            stage_chunk(co + 2, set ^ 1, 1);
        }

        // ---- even chunk: se2 + bfr reads, deferred epi(prev), MFMAs from se-quad
        {
            float sec0 = s_se2[ce * 32 + c16];
            float sec1 = s_se2[ce * 32 + 16 + c16];
#pragma unroll
            for (int tc = 0; tc < 2; ++tc)
#pragma unroll
                for (int j = 0; j < 4; ++j)
                    bfr[tc][j] = *(const bf16x8*)&s_bf[set][0][tc * 4 + j][lane];
            f32x4 c0 = (f32x4){sec0, sec0, sec0, sec0};
            f32x4 c1 = (f32x4){sec1, sec1, sec1, sec1};
            if (p != 0) epilogue(ce - 1, accO);
            __builtin_amdgcn_s_setprio(1);
#pragma unroll
            for (int tv = 0; tv < 2; ++tv) {
                accE[tv][0] = __builtin_amdgcn_mfma_f32_16x16x32_bf16(
                    af[tv][0], bfr[0][0], c0, 0, 0, 0);
                accE[tv][1] = __builtin_amdgcn_mfma_f32_16x16x32_bf16(
                    af[tv][0], bfr[1][0], c1, 0, 0, 0);
            }
#pragma unroll
            for (int s = 1; s < 6; ++s)
#pragma unroll
                for (int tv = 0; tv < 2; ++tv)
#pragma unroll
                    for (int tc = 0; tc < 2; ++tc)
                        accE[tv][tc] = __builtin_amdgcn_mfma_f32_16x16x32_bf16(
                            af[tv][sa[s]], bfr[tc][sb[s]], accE[tv][tc], 0, 0, 0);
            __builtin_amdgcn_s_setprio(0);
        }

        // ---- odd chunk (no barrier inside the pair)
        {
            float sec0 = s_se2[co * 32 + c16];
            float sec1 = s_se2[co * 32 + 16 + c16];
#pragma unroll
            for (int tc = 0; tc < 2; ++tc)
#pragma unroll
                for (int j = 0; j < 4; ++j)
                    bfr[tc][j] = *(const bf16x8*)&s_bf[set][1][tc * 4 + j][lane];
            f32x4 c0 = (f32x4){sec0, sec0, sec0, sec0};
            f32x4 c1 = (f32x4){sec1, sec1, sec1, sec1};
            epilogue(ce, accE);
            __builtin_amdgcn_s_setprio(1);
#pragma unroll
            for (int tv = 0; tv < 2; ++tv) {
                accO[tv][0] = __builtin_amdgcn_mfma_f32_16x16x32_bf16(
                    af[tv][0], bfr[0][0], c0, 0, 0, 0);
                accO[tv][1] = __builtin_amdgcn_mfma_f32_16x16x32_bf16(
                    af[tv][0], bfr[1][0], c1, 0, 0, 0);
            }
#pragma unroll
            for (int s = 1; s < 6; ++s)
#pragma unroll
                for (int tv = 0; tv < 2; ++tv)
#pragma unroll
                    for (int tc = 0; tc < 2; ++tc)
                        accO[tv][tc] = __builtin_amdgcn_mfma_f32_16x16x32_bf16(
                            af[tv][sa[s]], bfr[tc][sb[s]], accO[tv][tc], 0, 0, 0);
            __builtin_amdgcn_s_setprio(0);
        }
        set ^= 1;
    }
    epilogue(31, accO);

    // ---- cross-lane top-2 merge over the 16 col-lanes (bits 0-3 of lane)
#pragma unroll
    for (int m = 1; m < 16; m <<= 1)
#pragma unroll
        for (int s = 0; s < 8; ++s) {
            unsigned o1 = (unsigned)__shfl_xor((int)p1[s], m, 64);
            unsigned o2 = (unsigned)__shfl_xor((int)p2[s], m, 64);
            unsigned lo = p1[s] < o1 ? p1[s] : o1;
            unsigned hi = p1[s] < o1 ? o1 : p1[s];
            unsigned n2 = p2[s] < o2 ? p2[s] : o2;
            p2[s] = hi < n2 ? hi : n2;
            p1[s] = lo;
        }

    if (c16 == 0) {
#pragma unroll
        for (int s = 0; s < 8; ++s) {
            int tv = s >> 2, r = s & 3;
            int row = w * 32 + tv * 16 + q * 4 + r;    // block-local
            s_widx[row] = (int)(p1[s] & 1023u);
            if (p2[s] - p1[s] <= MARGIN_P) {
                int pos = atomicAdd((int*)(ws + CNT_OFF), 1);
                if (pos < LIST_CAP) ((int*)(ws + LIST_OFF))[pos] = nb + row;
            }
        }
    }
    __syncthreads();

    // ---- gather-write (stores coalesced across rows)
    {
        int r = t & 127, half = t >> 7;
        int widx = s_widx[r];
        const float4* er = (const float4*)(cb + (size_t)widx * D + half * 32);
        float* op = out + (size_t)b * (D * HW) + hw0 + r + (size_t)(half * 32) * HW;
#pragma unroll
        for (int i = 0; i < 8; ++i) {
            float4 v = er[i];
            op[(size_t)(i * 4 + 0) * HW] = v.x;
            op[(size_t)(i * 4 + 1) * HW] = v.y;
            op[(size_t)(i * 4 + 2) * HW] = v.z;
            op[(size_t)(i * 4 + 3) * HW] = v.w;
        }
    }
}

// --- rescore: exact fp32-emulated chain over all codes for flagged vectors ---
__global__ __launch_bounds__(64) void vq_rescore(const float* __restrict__ in,
                                                 const float* __restrict__ cb,
                                                 float* __restrict__ out,
                                                 char* __restrict__ ws) {
    int count = *(const int*)(ws + CNT_OFF);
    if (count > LIST_CAP) count = LIST_CAP;
    const int* list = (const int*)(ws + LIST_OFF);
    const float* seg = (const float*)(ws + SE_OFF);
    int lane = threadIdx.x;
    for (int i = blockIdx.x; i < count; i += gridDim.x) {
        int n = list[i];
        int b = n >> 12, hw = n & (HW - 1);
        const float* xin = in + (size_t)b * (D * HW) + hw;
        float x[D];
#pragma unroll
        for (int d = 0; d < D; ++d) x[d] = xin[(size_t)d * HW];
        float y[D];
#pragma unroll
        for (int d = 0; d < D; ++d) y[d] = __fadd_rn(x[d], x[d]);
        float sx = np_sumsq64(x);
        float best = 3.4e38f; int bidx = 0;
        for (int c = 0; c < 16; ++c) {
            int k = c * 64 + lane;                      // ascending k per lane
            const float4* e4 = (const float4*)(cb + (size_t)k * D);
            float acc = 0.f;
#pragma unroll
            for (int p = 0; p < 16; ++p) {              // exact sequential chain
                float4 ev = e4[p];
                acc = __fmaf_rn(y[p * 4 + 0], ev.x, acc);
                acc = __fmaf_rn(y[p * 4 + 1], ev.y, acc);
                acc = __fmaf_rn(y[p * 4 + 2], ev.z, acc);
                acc = __fmaf_rn(y[p * 4 + 3], ev.w, acc);
            }
            float dist = __fsub_rn(__fadd_rn(sx, seg[k]), acc);
            if (dist < best) { best = dist; bidx = k; }
        }
#pragma unroll
        for (int m = 1; m < 64; m <<= 1) {              // (val, idx) lex-min
            float ob = __shfl_xor(best, m, 64);
            int oi = __shfl_xor(bidx, m, 64);
            if (ob < best || (ob == best && oi < bidx)) { best = ob; bidx = oi; }
        }
        out[(size_t)b * (D * HW) + (size_t)lane * HW + hw] = cb[(size_t)bidx * D + lane];
    }
}

extern "C" void kernel_launch(void* const* d_in, const int* in_sizes, int n_in,
                              void* d_out, int out_size, void* d_ws, size_t ws_size,
                              hipStream_t stream) {
    const float* in = (const float*)d_in[0];
    const float* cb = (const float*)d_in[1];
    float* out = (float*)d_out;
    char* ws = (char*)d_ws;

    if (ws_size < (size_t)WS_NEED) return;   // fail visibly, never OOB

    prep_cb<<<dim3(K / 256), dim3(256), 0, stream>>>(cb, ws);
    vq_main<<<dim3(NTOTAL / 128), dim3(256), 0, stream>>>(in, cb, out, ws);
    vq_rescore<<<dim3(2048), dim3(64), 0, stream>>>(in, cb, out, ws);
}